// Round 15
// baseline (475.217 us; speedup 1.0000x reference)
//
#include <hip/hip_runtime.h>

// ---------------------------------------------------------------------------
// GINENet, N=50000, E=800000, D=128.
// Round 15: mm parallelism fix — NH=1/BM=64 (grid 782 -> 3 waves/SIMD, half
// the acc VGPRs); static weight folds merged into one launch. Rest = r14.
// ---------------------------------------------------------------------------

typedef unsigned short u16;
typedef unsigned int u32;

using bfrag = __attribute__((ext_vector_type(8))) short;  // 8 bf16
using ffrag = __attribute__((ext_vector_type(4))) float;  // 4 fp32 acc

__device__ __forceinline__ u16 f2b(float f) {
    u32 u = __float_as_uint(f);
    return (u16)((u + 0x7FFFu + ((u >> 16) & 1u)) >> 16);   // RNE
}
__device__ __forceinline__ float b2f(u16 h) {
    return __uint_as_float(((u32)h) << 16);
}
__device__ __forceinline__ float b2f_lo(u32 g) { return __uint_as_float(g << 16); }
__device__ __forceinline__ float b2f_hi(u32 g) { return __uint_as_float(g & 0xffff0000u); }

#define BN_EPS 1e-5f
#define BKT_SHIFT 6
#define BKT_NODES 64
#define NBKT_MAX 1024
#define SC_CHUNK 8192

// ================== CSR histogram + input bf16 conversion ===================
__global__ void histo_conv(const int* __restrict__ ei, int* __restrict__ cnt, int E,
                           const float4* __restrict__ src, uint2* __restrict__ dst, int n4) {
    int i = blockIdx.x * blockDim.x + threadIdx.x;
    if (i < E) atomicAdd(&cnt[ei[E + i]], 1);
    if (i < n4) {
        float4 v = src[i];
        uint2 o;
        o.x = (u32)f2b(v.x) | ((u32)f2b(v.y) << 16);
        o.y = (u32)f2b(v.z) | ((u32)f2b(v.w) << 16);
        dst[i] = o;
    }
}

__global__ void scan_block(const int* __restrict__ cnt, int* __restrict__ excl,
                           int* __restrict__ part, int n) {
    __shared__ int s[256];
    int t = threadIdx.x;
    int base = blockIdx.x * 1024 + t * 4;
    int v0 = (base + 0 < n) ? cnt[base + 0] : 0;
    int v1 = (base + 1 < n) ? cnt[base + 1] : 0;
    int v2 = (base + 2 < n) ? cnt[base + 2] : 0;
    int v3 = (base + 3 < n) ? cnt[base + 3] : 0;
    int tsum = v0 + v1 + v2 + v3;
    s[t] = tsum;
    __syncthreads();
    for (int off = 1; off < 256; off <<= 1) {
        int x = (t >= off) ? s[t - off] : 0;
        __syncthreads();
        s[t] += x;
        __syncthreads();
    }
    int tbase = s[t] - tsum;
    if (base + 0 < n) excl[base + 0] = tbase;
    if (base + 1 < n) excl[base + 1] = tbase + v0;
    if (base + 2 < n) excl[base + 2] = tbase + v0 + v1;
    if (base + 3 < n) excl[base + 3] = tbase + v0 + v1 + v2;
    if (t == 255) part[blockIdx.x] = s[255];
}

// merged carry+add: each block wave-reduces the (<=64) partial sums below it
__global__ __launch_bounds__(256)
void scan_addc(int* __restrict__ excl, const int* __restrict__ part, int n, int nb) {
    __shared__ int carryS;
    int bi = blockIdx.x;
    if (threadIdx.x < 64) {
        int lane = threadIdx.x;
        int v = (lane < nb && lane < bi) ? part[lane] : 0;
        for (int off = 32; off; off >>= 1) v += __shfl_down(v, off);
        if (lane == 0) carryS = v;
    }
    __syncthreads();
    int base = bi * 1024 + threadIdx.x * 4;
#pragma unroll
    for (int q = 0; q < 4; ++q) {
        int idx = base + q;
        if (idx < n) excl[idx] += carryS;
    }
}

// Two-level bucketed scatter (block-aggregated atomics).
__global__ __launch_bounds__(256)
void scatter_bkt2(const int* __restrict__ ei, const float* __restrict__ ea,
                  const int* __restrict__ startN, int* __restrict__ bfill,
                  int2* __restrict__ bedges, int E, int nbkt) {
    __shared__ int cntL[NBKT_MAX];
    __shared__ int baseL[NBKT_MAX];
    const int tid = threadIdx.x;
    const int e0 = blockIdx.x * SC_CHUNK;
    const int e1 = min(E, e0 + SC_CHUNK);
    for (int i = tid; i < nbkt; i += 256) cntL[i] = 0;
    __syncthreads();
    for (int j = e0 + tid; j < e1; j += 256)
        atomicAdd(&cntL[ei[E + j] >> BKT_SHIFT], 1);
    __syncthreads();
    for (int i = tid; i < nbkt; i += 256) {
        int c = cntL[i];
        baseL[i] = c ? (startN[i << BKT_SHIFT] + atomicAdd(&bfill[i], c)) : 0;
        cntL[i] = 0;   // reuse as cursor
    }
    __syncthreads();
    for (int j = e0 + tid; j < e1; j += 256) {
        int src = ei[j];
        int dst = ei[E + j];
        int b = dst >> BKT_SHIFT;
        int pos = baseL[b] + atomicAdd(&cntL[b], 1);
        bedges[pos] = make_int2(src | ((dst & (BKT_NODES - 1)) << 20),
                                __float_as_int(ea[j]));
    }
}

// Bucket-local compaction: bucket-ordered -> exact per-node CSR order.
__global__ __launch_bounds__(256)
void compact_bkt(const int2* __restrict__ bedges, const int* __restrict__ startN,
                 int2* __restrict__ srcEa, int n, int E) {
    __shared__ int fillL[BKT_NODES];
    int b = blockIdx.x;
    int v0 = b << BKT_SHIFT;
    int s0 = startN[v0];
    int vEnd = v0 + BKT_NODES;
    int e1 = (vEnd >= n) ? E : startN[vEnd];
    if (threadIdx.x < BKT_NODES) fillL[threadIdx.x] = 0;
    __syncthreads();
    for (int j = s0 + threadIdx.x; j < e1; j += 256) {
        int2 p = bedges[j];
        int dl = (p.x >> 20) & (BKT_NODES - 1);
        int pos = startN[v0 + dl] + atomicAdd(&fillL[dl], 1);
        srcEa[pos] = make_int2(p.x & 0xFFFFF, p.y);
    }
}

// ============ weight fold (+BN from raw stats) -> FRAGMENT-MAJOR ============
// WbSw[(((cf*NKT+kt)*64) + kg*16 + mrow)*8 + e] = bf16(W[cf*16+mrow][kt*32+kg*8+e]*sc)
// -> mm B-fragment load = base + lane*16B (one coalesced 1KB read).
__device__ __forceinline__
void fold_row(const float* __restrict__ W, const float* __restrict__ bias,
              const float* __restrict__ stA, const float* __restrict__ gA,
              const float* __restrict__ btA, int DA,
              const float* __restrict__ stB, const float* __restrict__ gB,
              const float* __restrict__ btB, int DB,
              u16* __restrict__ WbSw, float* __restrict__ biasp,
              int DOUT, float inv_n, int o, int lane) {
    int DIN = DA + DB;
    int NKT = DIN >> 5;
    int cf = o >> 4, mrow = o & 15;
    if (o >= DOUT) {                    // pad row: zeros
        for (int k = lane; k < DIN; k += 64) {
            int kt = k >> 5, kg = (k >> 3) & 3, e = k & 7;
            WbSw[(((cf * NKT + kt) << 6) + (kg << 4) + mrow) * 8 + e] = 0;
        }
        if (lane == 0) biasp[o] = 0.f;
        return;
    }
    float part = 0.f;
    for (int k = lane; k < DIN; k += 64) {
        float w = W[o * DIN + k];
        float sc = 1.f, sh = 0.f;
        if (k < DA) {
            if (stA) {
                float mu = stA[k] * inv_n;
                float var = stA[DA + k] * inv_n - mu * mu;
                sc = gA[k] * rsqrtf(var + BN_EPS);
                sh = fmaf(-mu, sc, btA[k]);
            }
        } else {
            int kb = k - DA;
            if (stB) {
                float mu = stB[kb] * inv_n;
                float var = stB[DB + kb] * inv_n - mu * mu;
                sc = gB[kb] * rsqrtf(var + BN_EPS);
                sh = fmaf(-mu, sc, btB[kb]);
            }
        }
        int kt = k >> 5, kg = (k >> 3) & 3, e = k & 7;
        WbSw[(((cf * NKT + kt) << 6) + (kg << 4) + mrow) * 8 + e] = f2b(w * sc);
        part += w * sh;
    }
    for (int off = 32; off; off >>= 1) part += __shfl_down(part, off);
    if (lane == 0) biasp[o] = bias[o] + part;
}

__global__ __launch_bounds__(64)
void fold_w(const float* __restrict__ W, const float* __restrict__ bias,
            const float* __restrict__ stA, const float* __restrict__ gA,
            const float* __restrict__ btA, int DA,
            const float* __restrict__ stB, const float* __restrict__ gB,
            const float* __restrict__ btB, int DB,
            u16* __restrict__ WbSw, float* __restrict__ biasp, int DOUT, float inv_n) {
    fold_row(W, bias, stA, gA, btA, DA, stB, gB, btB, DB, WbSw, biasp, DOUT,
             inv_n, blockIdx.x, threadIdx.x);
}

// static (identity-affine) folds of conv1+conv2 weights, one launch
__global__ __launch_bounds__(64)
void fold_w12(const float* __restrict__ w1, const float* __restrict__ b1,
              const float* __restrict__ w2, const float* __restrict__ b2,
              u16* __restrict__ Wb1, u16* __restrict__ Wb2,
              float* __restrict__ biasp) {
    int o = blockIdx.x;
    if (o < 128)
        fold_row(w1, b1, nullptr, nullptr, nullptr, 128, nullptr, nullptr, nullptr, 0,
                 Wb1, biasp + 0, 128, 0.f, o, threadIdx.x);
    else
        fold_row(w2, b2, nullptr, nullptr, nullptr, 128, nullptr, nullptr, nullptr, 0,
                 Wb2, biasp + 128, 64, 0.f, o - 128, threadIdx.x);
}

// =================== gather-side GINE aggregation ===========================
// One WAVE per node; lane = packed feature pair. BN affine inline from raw
// stats (nullable -> identity). Plain cached loads.
__global__ __launch_bounds__(256)
void agg_csr(const u32* __restrict__ x2, const float* __restrict__ ew,
             const float* __restrict__ eb, const int2* __restrict__ srcEa,
             const int* __restrict__ start, const int* __restrict__ cnt,
             const float* __restrict__ stats, const float* __restrict__ g,
             const float* __restrict__ bt, u32* __restrict__ agg2, int n, float inv_n) {
    int v = blockIdx.x * 4 + (threadIdx.x >> 6);
    if (v >= n) return;
    int lane = threadIdx.x & 63;
    int s0 = start[v];
    int deg = cnt[v];
    float w0 = ew[2 * lane], w1 = ew[2 * lane + 1];
    float b0 = eb[2 * lane], b1 = eb[2 * lane + 1];
    float sc0 = 1.f, sh0 = 0.f, sc1 = 1.f, sh1 = 0.f;
    if (stats) {
        float mu0 = stats[2 * lane] * inv_n;
        float va0 = stats[128 + 2 * lane] * inv_n - mu0 * mu0;
        sc0 = g[2 * lane] * rsqrtf(va0 + BN_EPS);
        sh0 = fmaf(-mu0, sc0, bt[2 * lane]);
        float mu1 = stats[2 * lane + 1] * inv_n;
        float va1 = stats[129 + 2 * lane] * inv_n - mu1 * mu1;
        sc1 = g[2 * lane + 1] * rsqrtf(va1 + BN_EPS);
        sh1 = fmaf(-mu1, sc1, bt[2 * lane + 1]);
    }
    float a0 = 0.f, a1 = 0.f;
    int j = 0;
    for (; j + 7 < deg; j += 8) {
        int2 p[8];
        u32 gg[8];
#pragma unroll
        for (int t = 0; t < 8; ++t) p[t] = srcEa[s0 + j + t];
#pragma unroll
        for (int t = 0; t < 8; ++t) gg[t] = x2[(long)p[t].x * 64 + lane];
#pragma unroll
        for (int t = 0; t < 8; ++t) {
            float eav = __int_as_float(p[t].y);
            a0 += fmaxf(fmaf(b2f_lo(gg[t]), sc0, sh0) + fmaf(eav, w0, b0), 0.f);
            a1 += fmaxf(fmaf(b2f_hi(gg[t]), sc1, sh1) + fmaf(eav, w1, b1), 0.f);
        }
    }
    for (; j < deg; ++j) {
        int2 p = srcEa[s0 + j];
        u32 gg = x2[(long)p.x * 64 + lane];
        float eav = __int_as_float(p.y);
        a0 += fmaxf(fmaf(b2f_lo(gg), sc0, sh0) + fmaf(eav, w0, b0), 0.f);
        a1 += fmaxf(fmaf(b2f_hi(gg), sc1, sh1) + fmaf(eav, w1, b1), 0.f);
    }
    u32 gs = x2[(long)v * 64 + lane];
    float r0 = fmaf(b2f_lo(gs), sc0, sh0) + a0;
    float r1 = fmaf(b2f_hi(gs), sc1, sh1) + a1;
    agg2[(long)v * 64 + lane] = (u32)f2b(r0) | ((u32)f2b(r1) << 16);
}

// ======================= MFMA matmul + relu + stats =========================
// Zero staging, NH=1: each wave owns one 16-row m-tile (BM=64/block, grid 782
// -> 3 waves/SIMD). A from global (64B-coalesced, L1-hot across kt); B from
// fragment-major global W (one coalesced 1KB per (cf,kt)). LDS = stats only.
// Inputs padded to 128-row multiples (pad rows read garbage, never stored).
template <int DIN0, int DIN1, int DOUTP, int DOUT>
__global__ __launch_bounds__(256)
void mm_mfma(const u16* __restrict__ in0, const u16* __restrict__ in1,
             const u16* __restrict__ WbSw, const float* __restrict__ biasp,
             u16* __restrict__ out, float* __restrict__ stats, int n) {
    constexpr int DIN = DIN0 + DIN1;
    constexpr int BM = 64;
    constexpr int NCF = DOUTP / 16;
    constexpr int NKT = DIN / 32;
    __shared__ float cs[2 * DOUTP];
    const int tid = threadIdx.x;
    const int row0 = blockIdx.x * BM;
    const int wv = tid >> 6;
    const int lane = tid & 63;
    const int mrow = lane & 15;
    const int kg = lane >> 4;

    ffrag acc[NCF];
#pragma unroll
    for (int cf = 0; cf < NCF; ++cf) acc[cf] = (ffrag){0.f, 0.f, 0.f, 0.f};

    const long r0w = row0 + wv * 16 + mrow;   // this lane's row
#pragma unroll
    for (int kt = 0; kt < NKT; ++kt) {
        const int gk = kt * 32 + kg * 8;
        const u16* src = (DIN1 == 0 || gk < DIN0)
                             ? (in0 + r0w * DIN0 + gk)
                             : (in1 + r0w * DIN1 + (gk - DIN0));
        bfrag a = *(const bfrag*)src;
#pragma unroll
        for (int cf = 0; cf < NCF; ++cf) {
            bfrag bb = *(const bfrag*)(WbSw + (((long)(cf * NKT + kt) << 6) + lane) * 8);
            acc[cf] = __builtin_amdgcn_mfma_f32_16x16x32_bf16(a, bb, acc[cf], 0, 0, 0);
        }
    }

    // ---- epilogue: bias + relu + bf16 store + column stats
    for (int i = tid; i < 2 * DOUTP; i += 256) cs[i] = 0.f;
    __syncthreads();

    const int col = lane & 15;
#pragma unroll
    for (int cf = 0; cf < NCF; ++cf) {
        int c = cf * 16 + col;
        if (DOUTP != DOUT && c >= DOUT) continue;
        float bv = biasp[c];
        float bsum = 0.f, bss = 0.f;
#pragma unroll
        for (int r = 0; r < 4; ++r) {
            int gr = row0 + wv * 16 + kg * 4 + r;
            if (gr < n) {
                float v = fmaxf(acc[cf][r] + bv, 0.f);
                out[(long)gr * DOUT + c] = f2b(v);
                bsum += v;
                bss += v * v;
            }
        }
        atomicAdd(&cs[c], bsum);
        atomicAdd(&cs[DOUT + c], bss);
    }
    __syncthreads();
    for (int i = tid; i < 2 * DOUT; i += 256) atomicAdd(&stats[i], cs[i]);
}

// ===================== final BN (raw stats -> output) =======================
__global__ void bn_apply_out(const u16* __restrict__ t, const float* __restrict__ stats,
                             const float* __restrict__ g, const float* __restrict__ beta,
                             float* __restrict__ out, int total, float inv_n) {
    int i = blockIdx.x * blockDim.x + threadIdx.x;
    if (i < total) {
        int c = i & 7;
        float mu = stats[c] * inv_n;
        float var = stats[8 + c] * inv_n - mu * mu;
        float sc = g[c] * rsqrtf(var + BN_EPS);
        out[i] = fmaf(b2f(t[i]) - mu, sc, beta[c]);
    }
}

// ============================ driver ========================================
extern "C" void kernel_launch(void* const* d_in, const int* in_sizes, int n_in,
                              void* d_out, int out_size, void* d_ws, size_t ws_size,
                              hipStream_t stream) {
    const float* x    = (const float*)d_in[0];
    const int*   ei   = (const int*)d_in[1];
    const float* ea   = (const float*)d_in[2];
    const float* elw  = (const float*)d_in[3];
    const float* elb  = (const float*)d_in[4];
    const float* c1w  = (const float*)d_in[5];
    const float* c1b  = (const float*)d_in[6];
    const float* c1g  = (const float*)d_in[7];
    const float* c1bt = (const float*)d_in[8];
    const float* c2w  = (const float*)d_in[9];
    const float* c2b  = (const float*)d_in[10];
    const float* c2g  = (const float*)d_in[11];
    const float* c2bt = (const float*)d_in[12];
    const float* l1w  = (const float*)d_in[13];
    const float* l1b  = (const float*)d_in[14];
    const float* l1g  = (const float*)d_in[15];
    const float* l1bt = (const float*)d_in[16];
    const float* m1w  = (const float*)d_in[17];
    const float* m1b  = (const float*)d_in[18];
    const float* m1g  = (const float*)d_in[19];
    const float* m1bt = (const float*)d_in[20];
    const float* m2w  = (const float*)d_in[21];
    const float* m2b  = (const float*)d_in[22];
    const float* m2g  = (const float*)d_in[23];
    const float* m2bt = (const float*)d_in[24];

    const int n = in_sizes[0] / 128;   // 50000
    const int E = in_sizes[2];         // 800000
    const float inv_n = 1.0f / (float)n;
    const int nbkt = (n + BKT_NODES - 1) / BKT_NODES;
    const size_t np = (size_t)((n + 127) & ~127);   // padded rows for mm tiles

    char* wp = (char*)d_ws;
    auto alloc = [&](size_t bytes) { char* p = wp; wp += (bytes + 31) & ~(size_t)31; return p; };

    float* stats  = (float*)alloc(1280 * 4);         // 5 layers x [sum|sumsq]
    float* biasp  = (float*)alloc(5 * 128 * 4);
    int*   cnt    = (int*)alloc((size_t)n * 4);
    int*   bfill  = (int*)alloc((size_t)nbkt * 4);   // contiguous after cnt
    int*   startA = (int*)alloc((size_t)n * 4);
    int*   part   = (int*)alloc(64 * 4);
    int2*  bedges = (int2*)alloc((size_t)E * 8);
    int2*  srcEa  = (int2*)alloc((size_t)E * 8);
    u16*   xb     = (u16*)alloc(np * 128 * 2);
    u16*   Ab     = (u16*)alloc(np * 128 * 2);
    u16*   T1     = (u16*)alloc(np * 128 * 2);
    u16*   T2     = (u16*)alloc(np * 64 * 2);
    u16*   T3     = (u16*)alloc(np * 96 * 2);
    u16*   T4     = (u16*)alloc(np * 96 * 2);
    u16*   T5     = (u16*)alloc(np * 8 * 2);
    u16*   Wb1    = (u16*)alloc(128 * 128 * 2);
    u16*   Wb2    = (u16*)alloc(64 * 128 * 2);
    u16*   Wb3    = (u16*)alloc(96 * 192 * 2);
    u16*   Wb4    = (u16*)alloc(96 * 96 * 2);
    u16*   Wb5    = (u16*)alloc(16 * 96 * 2);

    hipMemsetAsync(stats, 0, 1280 * 4, stream);
    hipMemsetAsync(cnt, 0, ((size_t)n + nbkt) * 4, stream);   // cnt + bfill

    const int ag_grid = (n + 3) / 4;
    const int mm_grid = (n + 63) / 64;
    const int nb = (n + 1023) / 1024;
    const int sc_grid = (E + SC_CHUNK - 1) / SC_CHUNK;
    const int hc_grid = (max(E, n * 32) + 255) / 256;

    // ---- CSR build (+ fused input conversion): histo -> scan -> scatter -> compact
    histo_conv<<<hc_grid, 256, 0, stream>>>(ei, cnt, E, (const float4*)x, (uint2*)xb, n * 32);
    scan_block<<<nb, 256, 0, stream>>>(cnt, startA, part, n);
    scan_addc<<<nb, 256, 0, stream>>>(startA, part, n, nb);
    scatter_bkt2<<<sc_grid, 256, 0, stream>>>(ei, ea, startA, bfill, bedges, E, nbkt);
    compact_bkt<<<nbkt, 256, 0, stream>>>(bedges, startA, srcEa, n, E);

    // ---- static (identity) weight folds — single launch
    fold_w12<<<192, 64, 0, stream>>>(c1w, c1b, c2w, c2b, Wb1, Wb2, biasp);

    // ---- conv1: agg(x) -> mm1 -> T1 (pre-BN), stats0
    agg_csr<<<ag_grid, 256, 0, stream>>>((const u32*)xb, elw, elb, srcEa, startA, cnt,
                                         nullptr, nullptr, nullptr, (u32*)Ab, n, inv_n);
    mm_mfma<128, 0, 128, 128><<<mm_grid, 256, 0, stream>>>(
        Ab, nullptr, Wb1, biasp + 0, T1, stats + 0, n);

    // ---- conv2: agg(BN(T1) inline) -> mm2 -> T2 (pre-BN), stats1
    agg_csr<<<ag_grid, 256, 0, stream>>>((const u32*)T1, elw, elb, srcEa, startA, cnt,
                                         stats + 0, c1g, c1bt, (u32*)Ab, n, inv_n);
    mm_mfma<128, 0, 64, 64><<<mm_grid, 256, 0, stream>>>(
        Ab, nullptr, Wb2, biasp + 128, T2, stats + 256, n);

    // ---- lin1: fold W3 from stats0+stats1, mm on raw [T1|T2]
    fold_w<<<96, 64, 0, stream>>>(l1w, l1b, stats + 0, c1g, c1bt, 128,
                                  stats + 256, c2g, c2bt, 64, Wb3, biasp + 256, 96, inv_n);
    mm_mfma<128, 64, 96, 96><<<mm_grid, 256, 0, stream>>>(
        T1, T2, Wb3, biasp + 256, T3, stats + 512, n);

    // ---- mlp1 layer1
    fold_w<<<96, 64, 0, stream>>>(m1w, m1b, stats + 512, l1g, l1bt, 96,
                                  nullptr, nullptr, nullptr, 0, Wb4, biasp + 384, 96, inv_n);
    mm_mfma<96, 0, 96, 96><<<mm_grid, 256, 0, stream>>>(
        T3, nullptr, Wb4, biasp + 384, T4, stats + 768, n);

    // ---- mlp1 layer2 (DOUT=8 pad 16)
    fold_w<<<16, 64, 0, stream>>>(m2w, m2b, stats + 768, m1g, m1bt, 96,
                                  nullptr, nullptr, nullptr, 0, Wb5, biasp + 512, 8, inv_n);
    mm_mfma<96, 0, 16, 8><<<mm_grid, 256, 0, stream>>>(
        T4, nullptr, Wb5, biasp + 512, T5, stats + 1024, n);

    // ---- final BN -> d_out
    bn_apply_out<<<(n * 8 + 255) / 256, 256, 0, stream>>>(T5, stats + 1024, m2g, m2bt,
                                                          (float*)d_out, n * 8, inv_n);
}

// Round 16
// 413.972 us; speedup vs baseline: 1.1479x; 1.1479x over previous
//
#include <hip/hip_runtime.h>

// ---------------------------------------------------------------------------
// GINENet, N=50000, E=800000, D=128.
// Round 16: revert mm to r14's NH=2/BM=128 zero-staging form (measured best;
// r15's NH=1 halved B-reuse per load and regressed). Keep merged fold_w12.
// ---------------------------------------------------------------------------

typedef unsigned short u16;
typedef unsigned int u32;

using bfrag = __attribute__((ext_vector_type(8))) short;  // 8 bf16
using ffrag = __attribute__((ext_vector_type(4))) float;  // 4 fp32 acc

__device__ __forceinline__ u16 f2b(float f) {
    u32 u = __float_as_uint(f);
    return (u16)((u + 0x7FFFu + ((u >> 16) & 1u)) >> 16);   // RNE
}
__device__ __forceinline__ float b2f(u16 h) {
    return __uint_as_float(((u32)h) << 16);
}
__device__ __forceinline__ float b2f_lo(u32 g) { return __uint_as_float(g << 16); }
__device__ __forceinline__ float b2f_hi(u32 g) { return __uint_as_float(g & 0xffff0000u); }

#define BN_EPS 1e-5f
#define BKT_SHIFT 6
#define BKT_NODES 64
#define NBKT_MAX 1024
#define SC_CHUNK 8192

// ================== CSR histogram + input bf16 conversion ===================
__global__ void histo_conv(const int* __restrict__ ei, int* __restrict__ cnt, int E,
                           const float4* __restrict__ src, uint2* __restrict__ dst, int n4) {
    int i = blockIdx.x * blockDim.x + threadIdx.x;
    if (i < E) atomicAdd(&cnt[ei[E + i]], 1);
    if (i < n4) {
        float4 v = src[i];
        uint2 o;
        o.x = (u32)f2b(v.x) | ((u32)f2b(v.y) << 16);
        o.y = (u32)f2b(v.z) | ((u32)f2b(v.w) << 16);
        dst[i] = o;
    }
}

__global__ void scan_block(const int* __restrict__ cnt, int* __restrict__ excl,
                           int* __restrict__ part, int n) {
    __shared__ int s[256];
    int t = threadIdx.x;
    int base = blockIdx.x * 1024 + t * 4;
    int v0 = (base + 0 < n) ? cnt[base + 0] : 0;
    int v1 = (base + 1 < n) ? cnt[base + 1] : 0;
    int v2 = (base + 2 < n) ? cnt[base + 2] : 0;
    int v3 = (base + 3 < n) ? cnt[base + 3] : 0;
    int tsum = v0 + v1 + v2 + v3;
    s[t] = tsum;
    __syncthreads();
    for (int off = 1; off < 256; off <<= 1) {
        int x = (t >= off) ? s[t - off] : 0;
        __syncthreads();
        s[t] += x;
        __syncthreads();
    }
    int tbase = s[t] - tsum;
    if (base + 0 < n) excl[base + 0] = tbase;
    if (base + 1 < n) excl[base + 1] = tbase + v0;
    if (base + 2 < n) excl[base + 2] = tbase + v0 + v1;
    if (base + 3 < n) excl[base + 3] = tbase + v0 + v1 + v2;
    if (t == 255) part[blockIdx.x] = s[255];
}

// merged carry+add: each block wave-reduces the (<=64) partial sums below it
__global__ __launch_bounds__(256)
void scan_addc(int* __restrict__ excl, const int* __restrict__ part, int n, int nb) {
    __shared__ int carryS;
    int bi = blockIdx.x;
    if (threadIdx.x < 64) {
        int lane = threadIdx.x;
        int v = (lane < nb && lane < bi) ? part[lane] : 0;
        for (int off = 32; off; off >>= 1) v += __shfl_down(v, off);
        if (lane == 0) carryS = v;
    }
    __syncthreads();
    int base = bi * 1024 + threadIdx.x * 4;
#pragma unroll
    for (int q = 0; q < 4; ++q) {
        int idx = base + q;
        if (idx < n) excl[idx] += carryS;
    }
}

// Two-level bucketed scatter (block-aggregated atomics).
__global__ __launch_bounds__(256)
void scatter_bkt2(const int* __restrict__ ei, const float* __restrict__ ea,
                  const int* __restrict__ startN, int* __restrict__ bfill,
                  int2* __restrict__ bedges, int E, int nbkt) {
    __shared__ int cntL[NBKT_MAX];
    __shared__ int baseL[NBKT_MAX];
    const int tid = threadIdx.x;
    const int e0 = blockIdx.x * SC_CHUNK;
    const int e1 = min(E, e0 + SC_CHUNK);
    for (int i = tid; i < nbkt; i += 256) cntL[i] = 0;
    __syncthreads();
    for (int j = e0 + tid; j < e1; j += 256)
        atomicAdd(&cntL[ei[E + j] >> BKT_SHIFT], 1);
    __syncthreads();
    for (int i = tid; i < nbkt; i += 256) {
        int c = cntL[i];
        baseL[i] = c ? (startN[i << BKT_SHIFT] + atomicAdd(&bfill[i], c)) : 0;
        cntL[i] = 0;   // reuse as cursor
    }
    __syncthreads();
    for (int j = e0 + tid; j < e1; j += 256) {
        int src = ei[j];
        int dst = ei[E + j];
        int b = dst >> BKT_SHIFT;
        int pos = baseL[b] + atomicAdd(&cntL[b], 1);
        bedges[pos] = make_int2(src | ((dst & (BKT_NODES - 1)) << 20),
                                __float_as_int(ea[j]));
    }
}

// Bucket-local compaction: bucket-ordered -> exact per-node CSR order.
__global__ __launch_bounds__(256)
void compact_bkt(const int2* __restrict__ bedges, const int* __restrict__ startN,
                 int2* __restrict__ srcEa, int n, int E) {
    __shared__ int fillL[BKT_NODES];
    int b = blockIdx.x;
    int v0 = b << BKT_SHIFT;
    int s0 = startN[v0];
    int vEnd = v0 + BKT_NODES;
    int e1 = (vEnd >= n) ? E : startN[vEnd];
    if (threadIdx.x < BKT_NODES) fillL[threadIdx.x] = 0;
    __syncthreads();
    for (int j = s0 + threadIdx.x; j < e1; j += 256) {
        int2 p = bedges[j];
        int dl = (p.x >> 20) & (BKT_NODES - 1);
        int pos = startN[v0 + dl] + atomicAdd(&fillL[dl], 1);
        srcEa[pos] = make_int2(p.x & 0xFFFFF, p.y);
    }
}

// ============ weight fold (+BN from raw stats) -> FRAGMENT-MAJOR ============
// WbSw[(((cf*NKT+kt)*64) + kg*16 + mrow)*8 + e] = bf16(W[cf*16+mrow][kt*32+kg*8+e]*sc)
// -> mm B-fragment load = base + lane*16B (one coalesced 1KB read).
__device__ __forceinline__
void fold_row(const float* __restrict__ W, const float* __restrict__ bias,
              const float* __restrict__ stA, const float* __restrict__ gA,
              const float* __restrict__ btA, int DA,
              const float* __restrict__ stB, const float* __restrict__ gB,
              const float* __restrict__ btB, int DB,
              u16* __restrict__ WbSw, float* __restrict__ biasp,
              int DOUT, float inv_n, int o, int lane) {
    int DIN = DA + DB;
    int NKT = DIN >> 5;
    int cf = o >> 4, mrow = o & 15;
    if (o >= DOUT) {                    // pad row: zeros
        for (int k = lane; k < DIN; k += 64) {
            int kt = k >> 5, kg = (k >> 3) & 3, e = k & 7;
            WbSw[(((cf * NKT + kt) << 6) + (kg << 4) + mrow) * 8 + e] = 0;
        }
        if (lane == 0) biasp[o] = 0.f;
        return;
    }
    float part = 0.f;
    for (int k = lane; k < DIN; k += 64) {
        float w = W[o * DIN + k];
        float sc = 1.f, sh = 0.f;
        if (k < DA) {
            if (stA) {
                float mu = stA[k] * inv_n;
                float var = stA[DA + k] * inv_n - mu * mu;
                sc = gA[k] * rsqrtf(var + BN_EPS);
                sh = fmaf(-mu, sc, btA[k]);
            }
        } else {
            int kb = k - DA;
            if (stB) {
                float mu = stB[kb] * inv_n;
                float var = stB[DB + kb] * inv_n - mu * mu;
                sc = gB[kb] * rsqrtf(var + BN_EPS);
                sh = fmaf(-mu, sc, btB[kb]);
            }
        }
        int kt = k >> 5, kg = (k >> 3) & 3, e = k & 7;
        WbSw[(((cf * NKT + kt) << 6) + (kg << 4) + mrow) * 8 + e] = f2b(w * sc);
        part += w * sh;
    }
    for (int off = 32; off; off >>= 1) part += __shfl_down(part, off);
    if (lane == 0) biasp[o] = bias[o] + part;
}

__global__ __launch_bounds__(64)
void fold_w(const float* __restrict__ W, const float* __restrict__ bias,
            const float* __restrict__ stA, const float* __restrict__ gA,
            const float* __restrict__ btA, int DA,
            const float* __restrict__ stB, const float* __restrict__ gB,
            const float* __restrict__ btB, int DB,
            u16* __restrict__ WbSw, float* __restrict__ biasp, int DOUT, float inv_n) {
    fold_row(W, bias, stA, gA, btA, DA, stB, gB, btB, DB, WbSw, biasp, DOUT,
             inv_n, blockIdx.x, threadIdx.x);
}

// static (identity-affine) folds of conv1+conv2 weights, one launch
__global__ __launch_bounds__(64)
void fold_w12(const float* __restrict__ w1, const float* __restrict__ b1,
              const float* __restrict__ w2, const float* __restrict__ b2,
              u16* __restrict__ Wb1, u16* __restrict__ Wb2,
              float* __restrict__ biasp) {
    int o = blockIdx.x;
    if (o < 128)
        fold_row(w1, b1, nullptr, nullptr, nullptr, 128, nullptr, nullptr, nullptr, 0,
                 Wb1, biasp + 0, 128, 0.f, o, threadIdx.x);
    else
        fold_row(w2, b2, nullptr, nullptr, nullptr, 128, nullptr, nullptr, nullptr, 0,
                 Wb2, biasp + 128, 64, 0.f, o - 128, threadIdx.x);
}

// =================== gather-side GINE aggregation ===========================
// One WAVE per node; lane = packed feature pair. BN affine inline from raw
// stats (nullable -> identity). Plain cached loads.
__global__ __launch_bounds__(256)
void agg_csr(const u32* __restrict__ x2, const float* __restrict__ ew,
             const float* __restrict__ eb, const int2* __restrict__ srcEa,
             const int* __restrict__ start, const int* __restrict__ cnt,
             const float* __restrict__ stats, const float* __restrict__ g,
             const float* __restrict__ bt, u32* __restrict__ agg2, int n, float inv_n) {
    int v = blockIdx.x * 4 + (threadIdx.x >> 6);
    if (v >= n) return;
    int lane = threadIdx.x & 63;
    int s0 = start[v];
    int deg = cnt[v];
    float w0 = ew[2 * lane], w1 = ew[2 * lane + 1];
    float b0 = eb[2 * lane], b1 = eb[2 * lane + 1];
    float sc0 = 1.f, sh0 = 0.f, sc1 = 1.f, sh1 = 0.f;
    if (stats) {
        float mu0 = stats[2 * lane] * inv_n;
        float va0 = stats[128 + 2 * lane] * inv_n - mu0 * mu0;
        sc0 = g[2 * lane] * rsqrtf(va0 + BN_EPS);
        sh0 = fmaf(-mu0, sc0, bt[2 * lane]);
        float mu1 = stats[2 * lane + 1] * inv_n;
        float va1 = stats[129 + 2 * lane] * inv_n - mu1 * mu1;
        sc1 = g[2 * lane + 1] * rsqrtf(va1 + BN_EPS);
        sh1 = fmaf(-mu1, sc1, bt[2 * lane + 1]);
    }
    float a0 = 0.f, a1 = 0.f;
    int j = 0;
    for (; j + 7 < deg; j += 8) {
        int2 p[8];
        u32 gg[8];
#pragma unroll
        for (int t = 0; t < 8; ++t) p[t] = srcEa[s0 + j + t];
#pragma unroll
        for (int t = 0; t < 8; ++t) gg[t] = x2[(long)p[t].x * 64 + lane];
#pragma unroll
        for (int t = 0; t < 8; ++t) {
            float eav = __int_as_float(p[t].y);
            a0 += fmaxf(fmaf(b2f_lo(gg[t]), sc0, sh0) + fmaf(eav, w0, b0), 0.f);
            a1 += fmaxf(fmaf(b2f_hi(gg[t]), sc1, sh1) + fmaf(eav, w1, b1), 0.f);
        }
    }
    for (; j < deg; ++j) {
        int2 p = srcEa[s0 + j];
        u32 gg = x2[(long)p.x * 64 + lane];
        float eav = __int_as_float(p.y);
        a0 += fmaxf(fmaf(b2f_lo(gg), sc0, sh0) + fmaf(eav, w0, b0), 0.f);
        a1 += fmaxf(fmaf(b2f_hi(gg), sc1, sh1) + fmaf(eav, w1, b1), 0.f);
    }
    u32 gs = x2[(long)v * 64 + lane];
    float r0 = fmaf(b2f_lo(gs), sc0, sh0) + a0;
    float r1 = fmaf(b2f_hi(gs), sc1, sh1) + a1;
    agg2[(long)v * 64 + lane] = (u32)f2b(r0) | ((u32)f2b(r1) << 16);
}

// ======================= MFMA matmul + relu + stats =========================
// r14 form (measured best): zero staging, NH=2/BM=128. A-fragments straight
// from global (64B-coalesced per 4 lanes, L1-hot across kt); B-fragments from
// fragment-major global W (one coalesced 1KB per (cf,kt), reused by 2 MFMAs).
// LDS = stats only. Inputs padded to 128-row multiples.
template <int DIN0, int DIN1, int DOUTP, int DOUT>
__global__ __launch_bounds__(256)
void mm_mfma(const u16* __restrict__ in0, const u16* __restrict__ in1,
             const u16* __restrict__ WbSw, const float* __restrict__ biasp,
             u16* __restrict__ out, float* __restrict__ stats, int n) {
    constexpr int DIN = DIN0 + DIN1;
    constexpr int BM = 128;
    constexpr int NH = 2;
    constexpr int NCF = DOUTP / 16;
    constexpr int NKT = DIN / 32;
    __shared__ float cs[2 * DOUTP];
    const int tid = threadIdx.x;
    const int row0 = blockIdx.x * BM;
    const int wv = tid >> 6;
    const int lane = tid & 63;
    const int mrow = lane & 15;
    const int kg = lane >> 4;

    ffrag acc[NH][NCF];
#pragma unroll
    for (int h = 0; h < NH; ++h)
#pragma unroll
        for (int cf = 0; cf < NCF; ++cf) acc[h][cf] = (ffrag){0.f, 0.f, 0.f, 0.f};

    const int r0w = row0 + wv * 16 + mrow;   // this lane's base row
#pragma unroll
    for (int kt = 0; kt < NKT; ++kt) {
        const int gk = kt * 32 + kg * 8;
        bfrag a[NH];
#pragma unroll
        for (int h = 0; h < NH; ++h) {
            long gr = r0w + h * 64;
            const u16* src = (DIN1 == 0 || gk < DIN0)
                                 ? (in0 + gr * DIN0 + gk)
                                 : (in1 + gr * DIN1 + (gk - DIN0));
            a[h] = *(const bfrag*)src;
        }
#pragma unroll
        for (int cf = 0; cf < NCF; ++cf) {
            bfrag bb = *(const bfrag*)(WbSw + (((long)(cf * NKT + kt) << 6) + lane) * 8);
#pragma unroll
            for (int h = 0; h < NH; ++h)
                acc[h][cf] = __builtin_amdgcn_mfma_f32_16x16x32_bf16(a[h], bb, acc[h][cf], 0, 0, 0);
        }
    }

    // ---- epilogue: bias + relu + bf16 store + column stats
    for (int i = tid; i < 2 * DOUTP; i += 256) cs[i] = 0.f;
    __syncthreads();

    const int col = lane & 15;
#pragma unroll
    for (int cf = 0; cf < NCF; ++cf) {
        int c = cf * 16 + col;
        if (DOUTP != DOUT && c >= DOUT) continue;
        float bv = biasp[c];
        float bsum = 0.f, bss = 0.f;
#pragma unroll
        for (int h = 0; h < NH; ++h) {
#pragma unroll
            for (int r = 0; r < 4; ++r) {
                int gr = row0 + h * 64 + wv * 16 + kg * 4 + r;
                if (gr < n) {
                    float v = fmaxf(acc[h][cf][r] + bv, 0.f);
                    out[(long)gr * DOUT + c] = f2b(v);
                    bsum += v;
                    bss += v * v;
                }
            }
        }
        atomicAdd(&cs[c], bsum);
        atomicAdd(&cs[DOUT + c], bss);
    }
    __syncthreads();
    for (int i = tid; i < 2 * DOUT; i += 256) atomicAdd(&stats[i], cs[i]);
}

// ===================== final BN (raw stats -> output) =======================
__global__ void bn_apply_out(const u16* __restrict__ t, const float* __restrict__ stats,
                             const float* __restrict__ g, const float* __restrict__ beta,
                             float* __restrict__ out, int total, float inv_n) {
    int i = blockIdx.x * blockDim.x + threadIdx.x;
    if (i < total) {
        int c = i & 7;
        float mu = stats[c] * inv_n;
        float var = stats[8 + c] * inv_n - mu * mu;
        float sc = g[c] * rsqrtf(var + BN_EPS);
        out[i] = fmaf(b2f(t[i]) - mu, sc, beta[c]);
    }
}

// ============================ driver ========================================
extern "C" void kernel_launch(void* const* d_in, const int* in_sizes, int n_in,
                              void* d_out, int out_size, void* d_ws, size_t ws_size,
                              hipStream_t stream) {
    const float* x    = (const float*)d_in[0];
    const int*   ei   = (const int*)d_in[1];
    const float* ea   = (const float*)d_in[2];
    const float* elw  = (const float*)d_in[3];
    const float* elb  = (const float*)d_in[4];
    const float* c1w  = (const float*)d_in[5];
    const float* c1b  = (const float*)d_in[6];
    const float* c1g  = (const float*)d_in[7];
    const float* c1bt = (const float*)d_in[8];
    const float* c2w  = (const float*)d_in[9];
    const float* c2b  = (const float*)d_in[10];
    const float* c2g  = (const float*)d_in[11];
    const float* c2bt = (const float*)d_in[12];
    const float* l1w  = (const float*)d_in[13];
    const float* l1b  = (const float*)d_in[14];
    const float* l1g  = (const float*)d_in[15];
    const float* l1bt = (const float*)d_in[16];
    const float* m1w  = (const float*)d_in[17];
    const float* m1b  = (const float*)d_in[18];
    const float* m1g  = (const float*)d_in[19];
    const float* m1bt = (const float*)d_in[20];
    const float* m2w  = (const float*)d_in[21];
    const float* m2b  = (const float*)d_in[22];
    const float* m2g  = (const float*)d_in[23];
    const float* m2bt = (const float*)d_in[24];

    const int n = in_sizes[0] / 128;   // 50000
    const int E = in_sizes[2];         // 800000
    const float inv_n = 1.0f / (float)n;
    const int nbkt = (n + BKT_NODES - 1) / BKT_NODES;
    const size_t np = (size_t)((n + 127) & ~127);   // padded rows for mm tiles

    char* wp = (char*)d_ws;
    auto alloc = [&](size_t bytes) { char* p = wp; wp += (bytes + 31) & ~(size_t)31; return p; };

    float* stats  = (float*)alloc(1280 * 4);         // 5 layers x [sum|sumsq]
    float* biasp  = (float*)alloc(5 * 128 * 4);
    int*   cnt    = (int*)alloc((size_t)n * 4);
    int*   bfill  = (int*)alloc((size_t)nbkt * 4);   // contiguous after cnt
    int*   startA = (int*)alloc((size_t)n * 4);
    int*   part   = (int*)alloc(64 * 4);
    int2*  bedges = (int2*)alloc((size_t)E * 8);
    int2*  srcEa  = (int2*)alloc((size_t)E * 8);
    u16*   xb     = (u16*)alloc(np * 128 * 2);
    u16*   Ab     = (u16*)alloc(np * 128 * 2);
    u16*   T1     = (u16*)alloc(np * 128 * 2);
    u16*   T2     = (u16*)alloc(np * 64 * 2);
    u16*   T3     = (u16*)alloc(np * 96 * 2);
    u16*   T4     = (u16*)alloc(np * 96 * 2);
    u16*   T5     = (u16*)alloc(np * 8 * 2);
    u16*   Wb1    = (u16*)alloc(128 * 128 * 2);
    u16*   Wb2    = (u16*)alloc(64 * 128 * 2);
    u16*   Wb3    = (u16*)alloc(96 * 192 * 2);
    u16*   Wb4    = (u16*)alloc(96 * 96 * 2);
    u16*   Wb5    = (u16*)alloc(16 * 96 * 2);

    hipMemsetAsync(stats, 0, 1280 * 4, stream);
    hipMemsetAsync(cnt, 0, ((size_t)n + nbkt) * 4, stream);   // cnt + bfill

    const int ag_grid = (n + 3) / 4;
    const int mm_grid = (n + 127) / 128;
    const int nb = (n + 1023) / 1024;
    const int sc_grid = (E + SC_CHUNK - 1) / SC_CHUNK;
    const int hc_grid = (max(E, n * 32) + 255) / 256;

    // ---- CSR build (+ fused input conversion): histo -> scan -> scatter -> compact
    histo_conv<<<hc_grid, 256, 0, stream>>>(ei, cnt, E, (const float4*)x, (uint2*)xb, n * 32);
    scan_block<<<nb, 256, 0, stream>>>(cnt, startA, part, n);
    scan_addc<<<nb, 256, 0, stream>>>(startA, part, n, nb);
    scatter_bkt2<<<sc_grid, 256, 0, stream>>>(ei, ea, startA, bfill, bedges, E, nbkt);
    compact_bkt<<<nbkt, 256, 0, stream>>>(bedges, startA, srcEa, n, E);

    // ---- static (identity) weight folds — single launch
    fold_w12<<<192, 64, 0, stream>>>(c1w, c1b, c2w, c2b, Wb1, Wb2, biasp);

    // ---- conv1: agg(x) -> mm1 -> T1 (pre-BN), stats0
    agg_csr<<<ag_grid, 256, 0, stream>>>((const u32*)xb, elw, elb, srcEa, startA, cnt,
                                         nullptr, nullptr, nullptr, (u32*)Ab, n, inv_n);
    mm_mfma<128, 0, 128, 128><<<mm_grid, 256, 0, stream>>>(
        Ab, nullptr, Wb1, biasp + 0, T1, stats + 0, n);

    // ---- conv2: agg(BN(T1) inline) -> mm2 -> T2 (pre-BN), stats1
    agg_csr<<<ag_grid, 256, 0, stream>>>((const u32*)T1, elw, elb, srcEa, startA, cnt,
                                         stats + 0, c1g, c1bt, (u32*)Ab, n, inv_n);
    mm_mfma<128, 0, 64, 64><<<mm_grid, 256, 0, stream>>>(
        Ab, nullptr, Wb2, biasp + 128, T2, stats + 256, n);

    // ---- lin1: fold W3 from stats0+stats1, mm on raw [T1|T2]
    fold_w<<<96, 64, 0, stream>>>(l1w, l1b, stats + 0, c1g, c1bt, 128,
                                  stats + 256, c2g, c2bt, 64, Wb3, biasp + 256, 96, inv_n);
    mm_mfma<128, 64, 96, 96><<<mm_grid, 256, 0, stream>>>(
        T1, T2, Wb3, biasp + 256, T3, stats + 512, n);

    // ---- mlp1 layer1
    fold_w<<<96, 64, 0, stream>>>(m1w, m1b, stats + 512, l1g, l1bt, 96,
                                  nullptr, nullptr, nullptr, 0, Wb4, biasp + 384, 96, inv_n);
    mm_mfma<96, 0, 96, 96><<<mm_grid, 256, 0, stream>>>(
        T3, nullptr, Wb4, biasp + 384, T4, stats + 768, n);

    // ---- mlp1 layer2 (DOUT=8 pad 16)
    fold_w<<<16, 64, 0, stream>>>(m2w, m2b, stats + 768, m1g, m1bt, 96,
                                  nullptr, nullptr, nullptr, 0, Wb5, biasp + 512, 8, inv_n);
    mm_mfma<96, 0, 16, 8><<<mm_grid, 256, 0, stream>>>(
        T4, nullptr, Wb5, biasp + 512, T5, stats + 1024, n);

    // ---- final BN -> d_out
    bn_apply_out<<<(n * 8 + 255) / 256, 256, 0, stream>>>(T5, stats + 1024, m2g, m2bt,
                                                          (float*)d_out, n * 8, inv_n);
}